// Round 1
// baseline (712.062 us; speedup 1.0000x reference)
//
#include <hip/hip_runtime.h>
#include <hip/hip_bf16.h>

// GraphSAGE 3-layer fused pipeline.
// Layer i: agg = segment_sum(x[src], dst); mean = agg/max(cnt,1);
//          h = mean@Wl + x[:n_tgt]@Wr + b; relu (layers 0,1); log_softmax (layer 2).
//
// ws layout (floats):
//   agg0 [60000*100] cnt0 [60000] agg1 [6000*256] cnt1 [6000]
//   agg2 [1024*256]  cnt2 [1024]  h0 [60000*256]  h1 [6000*256]
// First 7,865,168 floats (aggs+cnts) are zeroed each call with one memset.

// ---------------- scatter: wave-per-edge segment-sum ----------------
template <int D>
__global__ __launch_bounds__(256) void scatter_add_k(
    const float* __restrict__ xsrc, const int* __restrict__ src,
    const int* __restrict__ dst, float* __restrict__ agg,
    float* __restrict__ cnt, int E) {
  long long idx = (long long)blockIdx.x * 256 + threadIdx.x;
  int e = (int)(idx >> 6);   // wave (64 lanes) per edge
  int f = (int)(idx & 63);
  if (e >= E) return;
  int s = src[e];
  int d = dst[e];
  if (f == 0) atomicAdd(&cnt[d], 1.0f);
  const float* xr = xsrc + (long long)s * D;
  float* ar = agg + (long long)d * D;
#pragma unroll
  for (int k = f; k < D; k += 64) {
    atomicAdd(&ar[k], xr[k]);
  }
}

// ---------------- fused mean-divide + dual GEMM + bias + relu ----------------
// out[M][256] = relu( (agg/max(cnt,1)) @ Wl + xt @ Wr + b )
template <int K, int ROWS, bool RELU>
__global__ __launch_bounds__(256) void sage_gemm_k(
    const float* __restrict__ agg, const float* __restrict__ cnt,
    const float* __restrict__ xt, const float* __restrict__ Wl,
    const float* __restrict__ Wr, const float* __restrict__ b,
    float* __restrict__ out, int M) {
  constexpr int N = 256;
  __shared__ float sm[ROWS][K];
  __shared__ float sx[ROWS][K];
  const int row0 = blockIdx.x * ROWS;

  for (int t = threadIdx.x; t < ROWS * K; t += 256) {
    int r = t / K;
    int k = t - r * K;
    int gr = row0 + r;
    float vm = 0.f, vx = 0.f;
    if (gr < M) {
      float c = cnt[gr];
      c = c > 1.f ? c : 1.f;
      vm = agg[gr * K + k] / c;
      vx = xt[gr * K + k];
    }
    sm[r][k] = vm;
    sx[r][k] = vx;
  }
  __syncthreads();

  const int j = threadIdx.x;  // output column
  float acc[ROWS];
#pragma unroll
  for (int r = 0; r < ROWS; ++r) acc[r] = 0.f;

  for (int k4 = 0; k4 < K; k4 += 4) {
    float wl[4], wr[4];
#pragma unroll
    for (int u = 0; u < 4; ++u) {
      wl[u] = Wl[(k4 + u) * N + j];
      wr[u] = Wr[(k4 + u) * N + j];
    }
#pragma unroll
    for (int r = 0; r < ROWS; ++r) {
      const float4 m4 = *reinterpret_cast<const float4*>(&sm[r][k4]);
      const float4 x4 = *reinterpret_cast<const float4*>(&sx[r][k4]);
      acc[r] += m4.x * wl[0] + m4.y * wl[1] + m4.z * wl[2] + m4.w * wl[3] +
                x4.x * wr[0] + x4.y * wr[1] + x4.z * wr[2] + x4.w * wr[3];
    }
  }

  const float bias = b[j];
#pragma unroll
  for (int r = 0; r < ROWS; ++r) {
    int gr = row0 + r;
    if (gr < M) {
      float v = acc[r] + bias;
      if (RELU) v = fmaxf(v, 0.f);
      out[gr * N + j] = v;
    }
  }
}

// ---------------- final layer: dual GEMM (K=256 -> 47) + log_softmax ----------------
__global__ __launch_bounds__(64) void final_layer_k(
    const float* __restrict__ agg2, const float* __restrict__ cnt2,
    const float* __restrict__ h1, const float* __restrict__ Wl,
    const float* __restrict__ Wr, const float* __restrict__ bb,
    float* __restrict__ out) {
  __shared__ float sm[256];
  __shared__ float sx[256];
  const int i = blockIdx.x;
  float c = cnt2[i];
  c = c > 1.f ? c : 1.f;
  const float rc = 1.f / c;
  for (int k = threadIdx.x; k < 256; k += 64) {
    sm[k] = agg2[i * 256 + k] * rc;
    sx[k] = h1[i * 256 + k];
  }
  __syncthreads();

  const int j = threadIdx.x;
  float acc = -1e30f;
  if (j < 47) {
    float a = bb[j];
    for (int k = 0; k < 256; ++k) {
      a += sm[k] * Wl[k * 47 + j] + sx[k] * Wr[k * 47 + j];
    }
    acc = a;
  }
  // 64-lane reductions (wavefront = 64 on CDNA)
  float m = acc;
#pragma unroll
  for (int off = 32; off; off >>= 1) m = fmaxf(m, __shfl_xor(m, off));
  float e = (j < 47) ? expf(acc - m) : 0.f;
  float s = e;
#pragma unroll
  for (int off = 32; off; off >>= 1) s += __shfl_xor(s, off);
  const float lse = logf(s);
  if (j < 47) out[i * 47 + j] = acc - m - lse;
}

extern "C" void kernel_launch(void* const* d_in, const int* in_sizes, int n_in,
                              void* d_out, int out_size, void* d_ws, size_t ws_size,
                              hipStream_t stream) {
  const float* x    = (const float*)d_in[0];
  const int*   src0 = (const int*)d_in[1];
  const int*   dst0 = (const int*)d_in[2];
  const int*   src1 = (const int*)d_in[3];
  const int*   dst1 = (const int*)d_in[4];
  const int*   src2 = (const int*)d_in[5];
  const int*   dst2 = (const int*)d_in[6];
  const float* Wl0  = (const float*)d_in[7];
  const float* Wr0  = (const float*)d_in[8];
  const float* b0   = (const float*)d_in[9];
  const float* Wl1  = (const float*)d_in[10];
  const float* Wr1  = (const float*)d_in[11];
  const float* b1   = (const float*)d_in[12];
  const float* Wl2  = (const float*)d_in[13];
  const float* Wr2  = (const float*)d_in[14];
  const float* b2   = (const float*)d_in[15];
  float* out = (float*)d_out;

  const int E0 = in_sizes[1];  // 900000
  const int E1 = in_sizes[3];  // 60000
  const int E2 = in_sizes[5];  // 5120

  float* ws   = (float*)d_ws;
  float* agg0 = ws;                  // 60000*100
  float* cnt0 = agg0 + 6000000;      // 60000
  float* agg1 = cnt0 + 60000;        // 6000*256
  float* cnt1 = agg1 + 1536000;      // 6000
  float* agg2 = cnt1 + 6000;         // 1024*256
  float* cnt2 = agg2 + 262144;       // 1024
  float* h0   = cnt2 + 1024;         // 60000*256
  float* h1   = h0 + 15360000;       // 6000*256

  // zero all agg/cnt buffers in one shot (they are laid out contiguously)
  hipMemsetAsync(ws, 0, (size_t)7865168 * sizeof(float), stream);

  // Layer 0: 900000x100 gather -> 60000x100 segment sum
  {
    long long threads = (long long)E0 * 64;
    int blocks = (int)((threads + 255) / 256);
    scatter_add_k<100><<<blocks, 256, 0, stream>>>(x, src0, dst0, agg0, cnt0, E0);
    sage_gemm_k<100, 16, true><<<(60000 + 15) / 16, 256, 0, stream>>>(
        agg0, cnt0, x, Wl0, Wr0, b0, h0, 60000);
  }
  // Layer 1: 60000x256 -> 6000x256
  {
    long long threads = (long long)E1 * 64;
    int blocks = (int)((threads + 255) / 256);
    scatter_add_k<256><<<blocks, 256, 0, stream>>>(h0, src1, dst1, agg1, cnt1, E1);
    sage_gemm_k<256, 16, true><<<(6000 + 15) / 16, 256, 0, stream>>>(
        agg1, cnt1, h0, Wl1, Wr1, b1, h1, 6000);
  }
  // Layer 2: 6000x256 -> 1024x256 -> GEMM(47) + log_softmax
  {
    long long threads = (long long)E2 * 64;
    int blocks = (int)((threads + 255) / 256);
    scatter_add_k<256><<<blocks, 256, 0, stream>>>(h1, src2, dst2, agg2, cnt2, E2);
    final_layer_k<<<1024, 64, 0, stream>>>(agg2, cnt2, h1, Wl2, Wr2, b2, out);
  }
}

// Round 2
// 666.472 us; speedup vs baseline: 1.0684x; 1.0684x over previous
//
#include <hip/hip_runtime.h>
#include <hip/hip_bf16.h>

// GraphSAGE 3-layer fused pipeline, gather-based (no float atomics).
// Per layer: build CSR (hist -> scan -> fill src_sorted), then
//   mean[t] = (1/max(deg,1)) * sum_{e in seg(t)} x[src_sorted[e]]
//   h = mean@Wl + x[:n_tgt]@Wr + b ; relu (layers 0,1); log_softmax (layer 2).

// ---------------- CSR build ----------------
__global__ __launch_bounds__(256) void hist_k(const int* __restrict__ dst,
                                              int* __restrict__ cnt, int E) {
  int e = blockIdx.x * 256 + threadIdx.x;
  if (e < E) atomicAdd(&cnt[dst[e]], 1);
}

// single-block exclusive scan; writes row_start[0..n] and cursor[0..n-1]
__global__ __launch_bounds__(256) void scan_k(const int* __restrict__ cnt,
                                              int* __restrict__ row_start,
                                              int* __restrict__ cursor, int n) {
  __shared__ int sums[256];
  const int t = threadIdx.x;
  const int chunk = (n + 255) / 256;
  const int lo = t * chunk;
  const int hi = min(lo + chunk, n);
  int s = 0;
  for (int i = lo; i < hi; ++i) s += cnt[i];
  sums[t] = s;
  __syncthreads();
  for (int off = 1; off < 256; off <<= 1) {
    int v = (t >= off) ? sums[t - off] : 0;
    __syncthreads();
    sums[t] += v;
    __syncthreads();
  }
  int prefix = (t == 0) ? 0 : sums[t - 1];
  for (int i = lo; i < hi; ++i) {
    row_start[i] = prefix;
    cursor[i] = prefix;
    prefix += cnt[i];
  }
  if (t == 255) row_start[n] = sums[255];
}

__global__ __launch_bounds__(256) void fill_k(const int* __restrict__ src,
                                              const int* __restrict__ dst,
                                              int* __restrict__ cursor,
                                              int* __restrict__ src_sorted, int E) {
  int e = blockIdx.x * 256 + threadIdx.x;
  if (e < E) {
    int pos = atomicAdd(&cursor[dst[e]], 1);
    src_sorted[pos] = src[e];
  }
}

// ---------------- gather-reduce: wave per target, writes mean ----------------
template <int D>
__global__ __launch_bounds__(256) void gather_mean_k(
    const float* __restrict__ x, const int* __restrict__ src_sorted,
    const int* __restrict__ row_start, float* __restrict__ mean, int n) {
  int idx = blockIdx.x * 256 + threadIdx.x;
  int w = idx >> 6;  // wave per target row
  int f = idx & 63;
  if (w >= n) return;
  const int lo = row_start[w];
  const int hi = row_start[w + 1];
  constexpr int NR = (D + 63) / 64;
  float acc[NR];
#pragma unroll
  for (int r = 0; r < NR; ++r) acc[r] = 0.f;
  for (int e = lo; e < hi; ++e) {
    const float* xr = x + (long long)src_sorted[e] * D;
#pragma unroll
    for (int r = 0; r < NR; ++r) {
      int k = f + 64 * r;
      if (k < D) acc[r] += xr[k];
    }
  }
  const float inv = 1.f / (float)max(hi - lo, 1);
#pragma unroll
  for (int r = 0; r < NR; ++r) {
    int k = f + 64 * r;
    if (k < D) mean[(long long)w * D + k] = acc[r] * inv;
  }
}

// ---------------- dual GEMM + bias + relu ----------------
// out[M][256] = relu( mean @ Wl + xt @ Wr + b )
template <int K, int ROWS, bool RELU>
__global__ __launch_bounds__(256) void sage_gemm_k(
    const float* __restrict__ mean, const float* __restrict__ xt,
    const float* __restrict__ Wl, const float* __restrict__ Wr,
    const float* __restrict__ b, float* __restrict__ out, int M) {
  constexpr int N = 256;
  __shared__ float sm[ROWS][K];
  __shared__ float sx[ROWS][K];
  const int row0 = blockIdx.x * ROWS;

  for (int t = threadIdx.x; t < ROWS * K; t += 256) {
    int r = t / K;
    int k = t - r * K;
    int gr = row0 + r;
    float vm = 0.f, vx = 0.f;
    if (gr < M) {
      vm = mean[(long long)gr * K + k];
      vx = xt[(long long)gr * K + k];
    }
    sm[r][k] = vm;
    sx[r][k] = vx;
  }
  __syncthreads();

  const int j = threadIdx.x;  // output column
  float acc[ROWS];
#pragma unroll
  for (int r = 0; r < ROWS; ++r) acc[r] = 0.f;

  for (int k4 = 0; k4 < K; k4 += 4) {
    float wl[4], wr[4];
#pragma unroll
    for (int u = 0; u < 4; ++u) {
      wl[u] = Wl[(k4 + u) * N + j];
      wr[u] = Wr[(k4 + u) * N + j];
    }
#pragma unroll
    for (int r = 0; r < ROWS; ++r) {
      const float4 m4 = *reinterpret_cast<const float4*>(&sm[r][k4]);
      const float4 x4 = *reinterpret_cast<const float4*>(&sx[r][k4]);
      acc[r] += m4.x * wl[0] + m4.y * wl[1] + m4.z * wl[2] + m4.w * wl[3] +
                x4.x * wr[0] + x4.y * wr[1] + x4.z * wr[2] + x4.w * wr[3];
    }
  }

  const float bias = b[j];
#pragma unroll
  for (int r = 0; r < ROWS; ++r) {
    int gr = row0 + r;
    if (gr < M) {
      float v = acc[r] + bias;
      if (RELU) v = fmaxf(v, 0.f);
      out[(long long)gr * N + j] = v;
    }
  }
}

// ---------------- final layer: dual GEMM (K=256 -> 47) + log_softmax ----------------
__global__ __launch_bounds__(64) void final_layer_k(
    const float* __restrict__ mean2, const float* __restrict__ h1,
    const float* __restrict__ Wl, const float* __restrict__ Wr,
    const float* __restrict__ bb, float* __restrict__ out) {
  __shared__ float sm[256];
  __shared__ float sx[256];
  const int i = blockIdx.x;
  for (int k = threadIdx.x; k < 256; k += 64) {
    sm[k] = mean2[i * 256 + k];
    sx[k] = h1[i * 256 + k];
  }
  __syncthreads();

  const int j = threadIdx.x;
  float acc = -1e30f;
  if (j < 47) {
    float a = bb[j];
    for (int k = 0; k < 256; ++k) {
      a += sm[k] * Wl[k * 47 + j] + sx[k] * Wr[k * 47 + j];
    }
    acc = a;
  }
  float m = acc;
#pragma unroll
  for (int off = 32; off; off >>= 1) m = fmaxf(m, __shfl_xor(m, off));
  float e = (j < 47) ? expf(acc - m) : 0.f;
  float s = e;
#pragma unroll
  for (int off = 32; off; off >>= 1) s += __shfl_xor(s, off);
  const float lse = logf(s);
  if (j < 47) out[i * 47 + j] = acc - m - lse;
}

extern "C" void kernel_launch(void* const* d_in, const int* in_sizes, int n_in,
                              void* d_out, int out_size, void* d_ws, size_t ws_size,
                              hipStream_t stream) {
  const float* x    = (const float*)d_in[0];
  const int*   src0 = (const int*)d_in[1];
  const int*   dst0 = (const int*)d_in[2];
  const int*   src1 = (const int*)d_in[3];
  const int*   dst1 = (const int*)d_in[4];
  const int*   src2 = (const int*)d_in[5];
  const int*   dst2 = (const int*)d_in[6];
  const float* Wl0  = (const float*)d_in[7];
  const float* Wr0  = (const float*)d_in[8];
  const float* b0   = (const float*)d_in[9];
  const float* Wl1  = (const float*)d_in[10];
  const float* Wr1  = (const float*)d_in[11];
  const float* b1   = (const float*)d_in[12];
  const float* Wl2  = (const float*)d_in[13];
  const float* Wr2  = (const float*)d_in[14];
  const float* b2   = (const float*)d_in[15];
  float* out = (float*)d_out;

  const int E0 = in_sizes[1];  // 900000
  const int E1 = in_sizes[3];  // 60000
  const int E2 = in_sizes[5];  // 5120
  const int N0 = 60000, N1 = 6000, N2 = 1024;

  // ---- workspace carve-up (all 4-byte words) ----
  float* fw = (float*)d_ws;
  float* mean0 = fw;                    // 60000*100 = 6,000,000
  float* h0    = mean0 + 6000000;       // 60000*256 = 15,360,000
  float* mean1 = h0 + 15360000;         // 6000*256  = 1,536,000
  float* h1    = mean1 + 1536000;       // 6000*256  = 1,536,000
  float* mean2 = h1 + 1536000;          // 1024*256  = 262,144
  int* iw = (int*)(mean2 + 262144);
  int* row0 = iw;                       // 60001
  int* row1 = row0 + 60001;             // 6001
  int* row2 = row1 + 6001;              // 1025
  int* cnt0 = row2 + 1025;              // 60000  } contiguous: one memset
  int* cnt1 = cnt0 + 60000;             // 6000   }
  int* cnt2 = cnt1 + 6000;              // 1024   }
  int* cur0 = cnt2 + 1024;              // 60000
  int* cur1 = cur0 + 60000;             // 6000
  int* cur2 = cur1 + 6000;              // 1024
  int* ss0  = cur2 + 1024;              // 900000
  int* ss1  = ss0 + 900000;             // 60000
  int* ss2  = ss1 + 60000;              // 5120

  // zero the three histogram regions (contiguous, 67024 ints)
  hipMemsetAsync(cnt0, 0, (size_t)67024 * sizeof(int), stream);

  // ---- CSR build for all 3 layers ----
  hist_k<<<(E0 + 255) / 256, 256, 0, stream>>>(dst0, cnt0, E0);
  hist_k<<<(E1 + 255) / 256, 256, 0, stream>>>(dst1, cnt1, E1);
  hist_k<<<(E2 + 255) / 256, 256, 0, stream>>>(dst2, cnt2, E2);
  scan_k<<<1, 256, 0, stream>>>(cnt0, row0, cur0, N0);
  scan_k<<<1, 256, 0, stream>>>(cnt1, row1, cur1, N1);
  scan_k<<<1, 256, 0, stream>>>(cnt2, row2, cur2, N2);
  fill_k<<<(E0 + 255) / 256, 256, 0, stream>>>(src0, dst0, cur0, ss0, E0);
  fill_k<<<(E1 + 255) / 256, 256, 0, stream>>>(src1, dst1, cur1, ss1, E1);
  fill_k<<<(E2 + 255) / 256, 256, 0, stream>>>(src2, dst2, cur2, ss2, E2);

  // ---- Layer 0: 900000x100 gather -> 60000 means -> GEMM(100->256)+relu ----
  gather_mean_k<100><<<(N0 * 64 + 255) / 256, 256, 0, stream>>>(x, ss0, row0, mean0, N0);
  sage_gemm_k<100, 16, true><<<(N0 + 15) / 16, 256, 0, stream>>>(
      mean0, x, Wl0, Wr0, b0, h0, N0);

  // ---- Layer 1: 60000x256 -> 6000 ----
  gather_mean_k<256><<<(N1 * 64 + 255) / 256, 256, 0, stream>>>(h0, ss1, row1, mean1, N1);
  sage_gemm_k<256, 16, true><<<(N1 + 15) / 16, 256, 0, stream>>>(
      mean1, h0, Wl1, Wr1, b1, h1, N1);

  // ---- Layer 2: 6000x256 -> 1024 -> GEMM(47) + log_softmax ----
  gather_mean_k<256><<<(N2 * 64 + 255) / 256, 256, 0, stream>>>(h1, ss2, row2, mean2, N2);
  final_layer_k<<<N2, 64, 0, stream>>>(mean2, h1, Wl2, Wr2, b2, out);
}

// Round 3
// 496.274 us; speedup vs baseline: 1.4348x; 1.3430x over previous
//
#include <hip/hip_runtime.h>
#include <hip/hip_bf16.h>

// GraphSAGE 3-layer, gather-based CSR + bf16-MFMA GEMMs.
// Layer i: CSR(hist/scan/fill) -> gather_mean (bf16 out) -> A=[mean|x] (bf16)
//          -> MFMA GEMM vs packed B=[Wl;Wr] (bf16, fp32 accum) + bias (+relu)
// Final layer stays f32 vector (tiny: 1024x47, K=512) + fused log_softmax.

typedef short bf16x8 __attribute__((ext_vector_type(8)));
typedef float f32x4 __attribute__((ext_vector_type(4)));

static __device__ __forceinline__ unsigned short f2bf(float f) {
  unsigned u = __float_as_uint(f);
  unsigned r = u + 0x7FFFu + ((u >> 16) & 1u);  // RNE
  return (unsigned short)(r >> 16);
}

// ---------------- CSR build ----------------
__global__ __launch_bounds__(256) void hist_k(const int* __restrict__ dst,
                                              int* __restrict__ cnt, int E) {
  int e = blockIdx.x * 256 + threadIdx.x;
  if (e < E) atomicAdd(&cnt[dst[e]], 1);
}

__global__ __launch_bounds__(256) void scan_k(const int* __restrict__ cnt,
                                              int* __restrict__ row_start,
                                              int* __restrict__ cursor, int n) {
  __shared__ int sums[256];
  const int t = threadIdx.x;
  const int chunk = (n + 255) / 256;
  const int lo = t * chunk;
  const int hi = min(lo + chunk, n);
  int s = 0;
  for (int i = lo; i < hi; ++i) s += cnt[i];
  sums[t] = s;
  __syncthreads();
  for (int off = 1; off < 256; off <<= 1) {
    int v = (t >= off) ? sums[t - off] : 0;
    __syncthreads();
    sums[t] += v;
    __syncthreads();
  }
  int prefix = (t == 0) ? 0 : sums[t - 1];
  for (int i = lo; i < hi; ++i) {
    row_start[i] = prefix;
    cursor[i] = prefix;
    prefix += cnt[i];
  }
  if (t == 255) row_start[n] = sums[255];
}

__global__ __launch_bounds__(256) void fill_k(const int* __restrict__ src,
                                              const int* __restrict__ dst,
                                              int* __restrict__ cursor,
                                              int* __restrict__ src_sorted, int E) {
  int e = blockIdx.x * 256 + threadIdx.x;
  if (e < E) {
    int pos = atomicAdd(&cursor[dst[e]], 1);
    src_sorted[pos] = src[e];
  }
}

// ------------- gather-mean, bf16 output, 4-edge unrolled -------------
template <int D>
__global__ __launch_bounds__(256) void gather_mean_bf16_k(
    const float* __restrict__ x, const int* __restrict__ ss,
    const int* __restrict__ rs, unsigned short* __restrict__ out,
    int pitch, int n) {
  int idx = blockIdx.x * 256 + threadIdx.x;
  int w = idx >> 6;
  int f = idx & 63;
  if (w >= n) return;
  const int lo = rs[w];
  const int hi = rs[w + 1];
  constexpr int NR = (D + 63) / 64;
  float acc[NR];
#pragma unroll
  for (int r = 0; r < NR; ++r) acc[r] = 0.f;
  int e = lo;
  for (; e + 4 <= hi; e += 4) {
    const float* p0 = x + (size_t)ss[e] * D;
    const float* p1 = x + (size_t)ss[e + 1] * D;
    const float* p2 = x + (size_t)ss[e + 2] * D;
    const float* p3 = x + (size_t)ss[e + 3] * D;
#pragma unroll
    for (int r = 0; r < NR; ++r) {
      int k = f + 64 * r;
      if (k < D) acc[r] += (p0[k] + p1[k]) + (p2[k] + p3[k]);
    }
  }
  for (; e < hi; ++e) {
    const float* p0 = x + (size_t)ss[e] * D;
#pragma unroll
    for (int r = 0; r < NR; ++r) {
      int k = f + 64 * r;
      if (k < D) acc[r] += p0[k];
    }
  }
  const float inv = 1.f / (float)max(hi - lo, 1);
#pragma unroll
  for (int r = 0; r < NR; ++r) {
    int k = f + 64 * r;
    if (k < D) out[(size_t)w * pitch + k] = f2bf(acc[r] * inv);
  }
}

// f32-out variant for the final layer's mean2
template <int D>
__global__ __launch_bounds__(256) void gather_mean_f32_k(
    const float* __restrict__ x, const int* __restrict__ ss,
    const int* __restrict__ rs, float* __restrict__ out, int n) {
  int idx = blockIdx.x * 256 + threadIdx.x;
  int w = idx >> 6;
  int f = idx & 63;
  if (w >= n) return;
  const int lo = rs[w];
  const int hi = rs[w + 1];
  constexpr int NR = (D + 63) / 64;
  float acc[NR];
#pragma unroll
  for (int r = 0; r < NR; ++r) acc[r] = 0.f;
  int e = lo;
  for (; e + 4 <= hi; e += 4) {
    const float* p0 = x + (size_t)ss[e] * D;
    const float* p1 = x + (size_t)ss[e + 1] * D;
    const float* p2 = x + (size_t)ss[e + 2] * D;
    const float* p3 = x + (size_t)ss[e + 3] * D;
#pragma unroll
    for (int r = 0; r < NR; ++r) {
      int k = f + 64 * r;
      if (k < D) acc[r] += (p0[k] + p1[k]) + (p2[k] + p3[k]);
    }
  }
  for (; e < hi; ++e) {
    const float* p0 = x + (size_t)ss[e] * D;
#pragma unroll
    for (int r = 0; r < NR; ++r) {
      int k = f + 64 * r;
      if (k < D) acc[r] += p0[k];
    }
  }
  const float inv = 1.f / (float)max(hi - lo, 1);
#pragma unroll
  for (int r = 0; r < NR; ++r) {
    int k = f + 64 * r;
    if (k < D) out[(size_t)w * D + k] = acc[r] * inv;
  }
}

// ------------- x -> bf16 A-matrix x-part copy -------------
// am[t][off + k] = bf16(x[t*D + k]), one block per row
template <int D>
__global__ void xconv_k(const float* __restrict__ x,
                        unsigned short* __restrict__ am, int pitch, int off) {
  int t = blockIdx.x;
  int k = threadIdx.x;
  if (k < D) am[(size_t)t * pitch + off + k] = f2bf(x[(size_t)t * D + k]);
}

// ------------- B packing: bm[(k/8)][256][8] bf16, zero pad rows -------------
// val(k) = k<k1 ? W1[k][n] : (k2off<=k<k2off+k2 ? W2[k-k2off][n] : 0)
__global__ __launch_bounds__(256) void pack_b_k(
    const float* __restrict__ W1, const float* __restrict__ W2,
    unsigned short* __restrict__ bm, int k1, int k2off, int k2) {
  int k = blockIdx.x;
  int n = threadIdx.x;
  float v = 0.f;
  if (k < k1) v = W1[(size_t)k * 256 + n];
  else if (k >= k2off && k < k2off + k2) v = W2[(size_t)(k - k2off) * 256 + n];
  bm[(((size_t)(k >> 3) * 256) + n) * 8 + (k & 7)] = f2bf(v);
}

// ------------- MFMA GEMM: out[M][256] = A[M][KPAD] @ B[KPAD][256] + bias -------------
// A bf16 row-major pitch KPAD; B packed [(KPAD/8)][256][8] bf16; out f32.
template <int KPAD, int MBLK, bool RELU>
__global__ __launch_bounds__(256) void gemm_mfma_k(
    const unsigned short* __restrict__ A, const unsigned short* __restrict__ Bp,
    const float* __restrict__ bias, float* __restrict__ out, int M) {
  constexpr int LDA = KPAD + 8;           // bf16 units; keeps 16B align, breaks bank stride
  constexpr int CPR = KPAD / 8;           // 16B chunks per row
  constexpr int RT = MBLK / 16;           // row tiles per block
  constexpr int NKC = KPAD / 32;          // K chunks
  __shared__ unsigned short As[MBLK * LDA];

  const int row0 = blockIdx.x * MBLK;
  // stage A tile (16B chunks, coalesced)
  for (int t = threadIdx.x; t < MBLK * CPR; t += 256) {
    int r = t / CPR;
    int c = t - r * CPR;
    const uint4 v = *reinterpret_cast<const uint4*>(A + (size_t)(row0 + r) * KPAD + c * 8);
    *reinterpret_cast<uint4*>(&As[r * LDA + c * 8]) = v;
  }
  __syncthreads();

  const int wid = threadIdx.x >> 6;
  const int l = threadIdx.x & 63;
  const int l15 = l & 15;
  const int lhi = l >> 4;

  f32x4 acc[RT][4];
#pragma unroll
  for (int rt = 0; rt < RT; ++rt)
#pragma unroll
    for (int ct = 0; ct < 4; ++ct) acc[rt][ct] = (f32x4){0.f, 0.f, 0.f, 0.f};

  for (int kc = 0; kc < NKC; ++kc) {
    bf16x8 a[RT], b[4];
#pragma unroll
    for (int rt = 0; rt < RT; ++rt)
      a[rt] = *reinterpret_cast<const bf16x8*>(
          &As[(rt * 16 + l15) * LDA + kc * 32 + lhi * 8]);
#pragma unroll
    for (int ct = 0; ct < 4; ++ct) {
      int n = wid * 64 + ct * 16 + l15;
      b[ct] = *reinterpret_cast<const bf16x8*>(
          Bp + ((size_t)(kc * 4 + lhi) * 256 + n) * 8);
    }
#pragma unroll
    for (int rt = 0; rt < RT; ++rt)
#pragma unroll
      for (int ct = 0; ct < 4; ++ct)
        acc[rt][ct] = __builtin_amdgcn_mfma_f32_16x16x32_bf16(a[rt], b[ct],
                                                              acc[rt][ct], 0, 0, 0);
  }

#pragma unroll
  for (int rt = 0; rt < RT; ++rt) {
#pragma unroll
    for (int ct = 0; ct < 4; ++ct) {
      int col = wid * 64 + ct * 16 + l15;
      float bv = bias[col];
#pragma unroll
      for (int r = 0; r < 4; ++r) {
        int row = row0 + rt * 16 + lhi * 4 + r;
        if (row < M) {
          float v = acc[rt][ct][r] + bv;
          if (RELU) v = fmaxf(v, 0.f);
          out[(size_t)row * 256 + col] = v;
        }
      }
    }
  }
}

// ------------- final: 4 rows/block, dual GEMM K=256+256 -> 47, log_softmax -------------
__global__ __launch_bounds__(64) void final4_k(
    const float* __restrict__ mean2, const float* __restrict__ h1,
    const float* __restrict__ Wl, const float* __restrict__ Wr,
    const float* __restrict__ bb, float* __restrict__ out) {
  const int i0 = blockIdx.x * 4;
  const int j = threadIdx.x;
  float acc[4] = {-1e30f, -1e30f, -1e30f, -1e30f};
  if (j < 47) {
    float b = bb[j];
    acc[0] = b; acc[1] = b; acc[2] = b; acc[3] = b;
    for (int k = 0; k < 256; ++k) {
      float wl = Wl[k * 47 + j];
      float wr = Wr[k * 47 + j];
#pragma unroll
      for (int r = 0; r < 4; ++r) {
        acc[r] += mean2[(size_t)(i0 + r) * 256 + k] * wl +
                  h1[(size_t)(i0 + r) * 256 + k] * wr;
      }
    }
  }
#pragma unroll
  for (int r = 0; r < 4; ++r) {
    float m = acc[r];
#pragma unroll
    for (int off = 32; off; off >>= 1) m = fmaxf(m, __shfl_xor(m, off));
    float e = (j < 47) ? expf(acc[r] - m) : 0.f;
    float s = e;
#pragma unroll
    for (int off = 32; off; off >>= 1) s += __shfl_xor(s, off);
    if (j < 47) out[(size_t)(i0 + r) * 47 + j] = acc[r] - m - logf(s);
  }
}

extern "C" void kernel_launch(void* const* d_in, const int* in_sizes, int n_in,
                              void* d_out, int out_size, void* d_ws, size_t ws_size,
                              hipStream_t stream) {
  const float* x    = (const float*)d_in[0];
  const int*   src0 = (const int*)d_in[1];
  const int*   dst0 = (const int*)d_in[2];
  const int*   src1 = (const int*)d_in[3];
  const int*   dst1 = (const int*)d_in[4];
  const int*   src2 = (const int*)d_in[5];
  const int*   dst2 = (const int*)d_in[6];
  const float* Wl0  = (const float*)d_in[7];
  const float* Wr0  = (const float*)d_in[8];
  const float* b0   = (const float*)d_in[9];
  const float* Wl1  = (const float*)d_in[10];
  const float* Wr1  = (const float*)d_in[11];
  const float* b1   = (const float*)d_in[12];
  const float* Wl2  = (const float*)d_in[13];
  const float* Wr2  = (const float*)d_in[14];
  const float* b2   = (const float*)d_in[15];
  float* out = (float*)d_out;

  const int E0 = in_sizes[1];  // 900000
  const int E1 = in_sizes[3];  // 60000
  const int E2 = in_sizes[5];  // 5120
  const int N0 = 60000, N1 = 6000, N2 = 1024;

  // ---- workspace carve-up (byte offsets, all 256B-aligned) ----
  char* base = (char*)d_ws;
  unsigned short* am0 = (unsigned short*)(base);            // 60032 x 224 bf16
  unsigned short* bm0 = (unsigned short*)(base + 26894336); // 28x256x8 bf16
  float* h0           = (float*)(base + 27009024);          // 60032 x 256 f32
  unsigned short* am1 = (unsigned short*)(base + 88481792); // 6016 x 512 bf16
  unsigned short* bm1 = (unsigned short*)(base + 94642176); // 64x256x8 bf16
  float* h1           = (float*)(base + 94904320);          // 6016 x 256 f32
  float* mean2        = (float*)(base + 101064704);         // 1024 x 256 f32
  int* iw   = (int*)(base + 102113280);
  int* row0 = iw;                       // 60001
  int* row1 = row0 + 60001;             // 6001
  int* row2 = row1 + 6001;              // 1025
  int* cnt0 = row2 + 1025;              // 60000 } contiguous: one memset
  int* cnt1 = cnt0 + 60000;             // 6000  }
  int* cnt2 = cnt1 + 6000;              // 1024  }
  int* cur0 = cnt2 + 1024;              // 60000
  int* cur1 = cur0 + 60000;             // 6000
  int* cur2 = cur1 + 6000;              // 1024
  int* ss0  = cur2 + 1024;              // 900000
  int* ss1  = ss0 + 900000;             // 60000
  int* ss2  = ss1 + 60000;              // 5120

  hipMemsetAsync(cnt0, 0, (size_t)67024 * sizeof(int), stream);

  // ---- CSR build ----
  hist_k<<<(E0 + 255) / 256, 256, 0, stream>>>(dst0, cnt0, E0);
  hist_k<<<(E1 + 255) / 256, 256, 0, stream>>>(dst1, cnt1, E1);
  hist_k<<<(E2 + 255) / 256, 256, 0, stream>>>(dst2, cnt2, E2);
  scan_k<<<1, 256, 0, stream>>>(cnt0, row0, cur0, N0);
  scan_k<<<1, 256, 0, stream>>>(cnt1, row1, cur1, N1);
  scan_k<<<1, 256, 0, stream>>>(cnt2, row2, cur2, N2);
  fill_k<<<(E0 + 255) / 256, 256, 0, stream>>>(src0, dst0, cur0, ss0, E0);
  fill_k<<<(E1 + 255) / 256, 256, 0, stream>>>(src1, dst1, cur1, ss1, E1);
  fill_k<<<(E2 + 255) / 256, 256, 0, stream>>>(src2, dst2, cur2, ss2, E2);

  // ---- weight packing (bf16, fragment order, zero pad rows) ----
  pack_b_k<<<224, 256, 0, stream>>>(Wl0, Wr0, bm0, 100, 112, 100);
  pack_b_k<<<512, 256, 0, stream>>>(Wl1, Wr1, bm1, 256, 256, 256);

  // ---- Layer 0 ----
  gather_mean_bf16_k<100><<<(N0 * 64 + 255) / 256, 256, 0, stream>>>(
      x, ss0, row0, am0, 224, N0);
  xconv_k<100><<<N0, 128, 0, stream>>>(x, am0, 224, 112);
  gemm_mfma_k<224, 64, true><<<(N0 + 63) / 64, 256, 0, stream>>>(
      am0, bm0, b0, h0, N0);

  // ---- Layer 1 ----
  gather_mean_bf16_k<256><<<(N1 * 64 + 255) / 256, 256, 0, stream>>>(
      h0, ss1, row1, am1, 512, N1);
  xconv_k<256><<<N1, 256, 0, stream>>>(h0, am1, 512, 256);
  gemm_mfma_k<512, 32, true><<<(N1 + 31) / 32, 256, 0, stream>>>(
      am1, bm1, b1, h1, N1);

  // ---- Layer 2 (final) ----
  gather_mean_f32_k<256><<<(N2 * 64 + 255) / 256, 256, 0, stream>>>(
      h1, ss2, row2, mean2, N2);
  final4_k<<<N2 / 4, 64, 0, stream>>>(mean2, h1, Wl2, Wr2, b2, out);
}

// Round 4
// 429.924 us; speedup vs baseline: 1.6563x; 1.1543x over previous
//
#include <hip/hip_runtime.h>
#include <hip/hip_bf16.h>

// GraphSAGE 3-layer, gather-based CSR + bf16-MFMA GEMMs. Consolidated:
//   memset, hist3, scan3, fill3, pack2, gather0(+xconv), gemm0,
//   gather1(+xconv), gemm1, final(gather2+gemm+log_softmax)  = 10 dispatches.

typedef short bf16x8 __attribute__((ext_vector_type(8)));
typedef float f32x4 __attribute__((ext_vector_type(4)));

static __device__ __forceinline__ unsigned short f2bf(float f) {
  unsigned u = __float_as_uint(f);
  unsigned r = u + 0x7FFFu + ((u >> 16) & 1u);  // RNE
  return (unsigned short)(r >> 16);
}

// ---------------- CSR build: one kernel per stage for all 3 layers ----------------
__global__ __launch_bounds__(256) void hist3_k(
    const int* __restrict__ d0, const int* __restrict__ d1, const int* __restrict__ d2,
    int* __restrict__ c0, int* __restrict__ c1, int* __restrict__ c2,
    int E0, int E1, int E2) {
  int t = blockIdx.x * 256 + threadIdx.x;
  if (t < E0) atomicAdd(&c0[d0[t]], 1);
  else if (t < E0 + E1) atomicAdd(&c1[d1[t - E0]], 1);
  else if (t < E0 + E1 + E2) atomicAdd(&c2[d2[t - E0 - E1]], 1);
}

__global__ __launch_bounds__(1024) void scan3_k(
    const int* __restrict__ c0, int* __restrict__ r0, int* __restrict__ u0,
    const int* __restrict__ c1, int* __restrict__ r1, int* __restrict__ u1,
    const int* __restrict__ c2, int* __restrict__ r2, int* __restrict__ u2,
    int n0, int n1, int n2) {
  const int* cnt; int* row; int* cur; int n;
  if (blockIdx.x == 0)      { cnt = c0; row = r0; cur = u0; n = n0; }
  else if (blockIdx.x == 1) { cnt = c1; row = r1; cur = u1; n = n1; }
  else                      { cnt = c2; row = r2; cur = u2; n = n2; }
  __shared__ int sums[1024];
  const int t = threadIdx.x;
  const int chunk = (n + 1023) / 1024;
  const int lo = t * chunk;
  const int hi = min(lo + chunk, n);
  int s = 0;
  for (int i = lo; i < hi; ++i) s += cnt[i];
  sums[t] = s;
  __syncthreads();
  for (int off = 1; off < 1024; off <<= 1) {
    int v = (t >= off) ? sums[t - off] : 0;
    __syncthreads();
    sums[t] += v;
    __syncthreads();
  }
  int prefix = (t == 0) ? 0 : sums[t - 1];
  for (int i = lo; i < hi; ++i) {
    row[i] = prefix;
    cur[i] = prefix;
    prefix += cnt[i];
  }
  if (t == 1023) row[n] = sums[1023];
}

__global__ __launch_bounds__(256) void fill3_k(
    const int* __restrict__ s0, const int* __restrict__ d0,
    const int* __restrict__ s1, const int* __restrict__ d1,
    const int* __restrict__ s2, const int* __restrict__ d2,
    int* __restrict__ u0, int* __restrict__ u1, int* __restrict__ u2,
    int* __restrict__ o0, int* __restrict__ o1, int* __restrict__ o2,
    int E0, int E1, int E2) {
  int t = blockIdx.x * 256 + threadIdx.x;
  if (t < E0) {
    int pos = atomicAdd(&u0[d0[t]], 1);
    o0[pos] = s0[t];
  } else if (t < E0 + E1) {
    int e = t - E0;
    int pos = atomicAdd(&u1[d1[e]], 1);
    o1[pos] = s1[e];
  } else if (t < E0 + E1 + E2) {
    int e = t - E0 - E1;
    int pos = atomicAdd(&u2[d2[e]], 1);
    o2[pos] = s2[e];
  }
}

// ------------- gather-mean + self-row conversion, bf16 A-matrix out -------------
// am[w][0..D)      = bf16( mean of x[src] rows )
// am[w][XOFF..XOFF+D) = bf16( xt[w] )
template <int D, int PITCH, int XOFF>
__global__ __launch_bounds__(256) void gather_fused_k(
    const float* __restrict__ x, const float* __restrict__ xt,
    const int* __restrict__ ss, const int* __restrict__ rs,
    unsigned short* __restrict__ am, int n) {
  int idx = blockIdx.x * 256 + threadIdx.x;
  int w = idx >> 6;
  int f = idx & 63;
  if (w >= n) return;
  const int lo = rs[w];
  const int hi = rs[w + 1];
  constexpr int NR = (D + 63) / 64;
  float acc[NR];
#pragma unroll
  for (int r = 0; r < NR; ++r) acc[r] = 0.f;
  int e = lo;
  for (; e + 4 <= hi; e += 4) {
    const float* p0 = x + (size_t)ss[e] * D;
    const float* p1 = x + (size_t)ss[e + 1] * D;
    const float* p2 = x + (size_t)ss[e + 2] * D;
    const float* p3 = x + (size_t)ss[e + 3] * D;
#pragma unroll
    for (int r = 0; r < NR; ++r) {
      int k = f + 64 * r;
      if (k < D) acc[r] += (p0[k] + p1[k]) + (p2[k] + p3[k]);
    }
  }
  for (; e < hi; ++e) {
    const float* p0 = x + (size_t)ss[e] * D;
#pragma unroll
    for (int r = 0; r < NR; ++r) {
      int k = f + 64 * r;
      if (k < D) acc[r] += p0[k];
    }
  }
  const float inv = 1.f / (float)max(hi - lo, 1);
  unsigned short* arow = am + (size_t)w * PITCH;
#pragma unroll
  for (int r = 0; r < NR; ++r) {
    int k = f + 64 * r;
    if (k < D) arow[k] = f2bf(acc[r] * inv);
  }
  const float* xrow = xt + (size_t)w * D;
#pragma unroll
  for (int r = 0; r < NR; ++r) {
    int k = f + 64 * r;
    if (k < D) arow[XOFF + k] = f2bf(xrow[k]);
  }
}

// ------------- B packing for both layers: bm[(k/8)][256][8] bf16 -------------
__global__ __launch_bounds__(256) void pack2_k(
    const float* __restrict__ Wl0, const float* __restrict__ Wr0,
    unsigned short* __restrict__ bm0,
    const float* __restrict__ Wl1, const float* __restrict__ Wr1,
    unsigned short* __restrict__ bm1) {
  int b = blockIdx.x;
  int n = threadIdx.x;
  if (b < 224) {
    int k = b;
    float v = 0.f;
    if (k < 100) v = Wl0[(size_t)k * 256 + n];
    else if (k >= 112 && k < 212) v = Wr0[(size_t)(k - 112) * 256 + n];
    bm0[(((size_t)(k >> 3) * 256) + n) * 8 + (k & 7)] = f2bf(v);
  } else {
    int k = b - 224;
    float v = (k < 256) ? Wl1[(size_t)k * 256 + n] : Wr1[(size_t)(k - 256) * 256 + n];
    bm1[(((size_t)(k >> 3) * 256) + n) * 8 + (k & 7)] = f2bf(v);
  }
}

// ------------- MFMA GEMM: out[M][256] = A[M][KPAD] @ B[KPAD][256] + bias -------------
template <int KPAD, int MBLK, bool RELU>
__global__ __launch_bounds__(256) void gemm_mfma_k(
    const unsigned short* __restrict__ A, const unsigned short* __restrict__ Bp,
    const float* __restrict__ bias, float* __restrict__ out, int M) {
  constexpr int LDA = KPAD + 8;
  constexpr int CPR = KPAD / 8;
  constexpr int RT = MBLK / 16;
  constexpr int NKC = KPAD / 32;
  __shared__ unsigned short As[MBLK * LDA];

  const int row0 = blockIdx.x * MBLK;
  for (int t = threadIdx.x; t < MBLK * CPR; t += 256) {
    int r = t / CPR;
    int c = t - r * CPR;
    const uint4 v = *reinterpret_cast<const uint4*>(A + (size_t)(row0 + r) * KPAD + c * 8);
    *reinterpret_cast<uint4*>(&As[r * LDA + c * 8]) = v;
  }
  __syncthreads();

  const int wid = threadIdx.x >> 6;
  const int l = threadIdx.x & 63;
  const int l15 = l & 15;
  const int lhi = l >> 4;

  f32x4 acc[RT][4];
#pragma unroll
  for (int rt = 0; rt < RT; ++rt)
#pragma unroll
    for (int ct = 0; ct < 4; ++ct) acc[rt][ct] = (f32x4){0.f, 0.f, 0.f, 0.f};

  for (int kc = 0; kc < NKC; ++kc) {
    bf16x8 a[RT], b[4];
#pragma unroll
    for (int rt = 0; rt < RT; ++rt)
      a[rt] = *reinterpret_cast<const bf16x8*>(
          &As[(rt * 16 + l15) * LDA + kc * 32 + lhi * 8]);
#pragma unroll
    for (int ct = 0; ct < 4; ++ct) {
      int n = wid * 64 + ct * 16 + l15;
      b[ct] = *reinterpret_cast<const bf16x8*>(
          Bp + ((size_t)(kc * 4 + lhi) * 256 + n) * 8);
    }
#pragma unroll
    for (int rt = 0; rt < RT; ++rt)
#pragma unroll
      for (int ct = 0; ct < 4; ++ct)
        acc[rt][ct] = __builtin_amdgcn_mfma_f32_16x16x32_bf16(a[rt], b[ct],
                                                              acc[rt][ct], 0, 0, 0);
  }

#pragma unroll
  for (int rt = 0; rt < RT; ++rt) {
#pragma unroll
    for (int ct = 0; ct < 4; ++ct) {
      int col = wid * 64 + ct * 16 + l15;
      float bv = bias[col];
#pragma unroll
      for (int r = 0; r < 4; ++r) {
        int row = row0 + rt * 16 + lhi * 4 + r;
        if (row < M) {
          float v = acc[rt][ct][r] + bv;
          if (RELU) v = fmaxf(v, 0.f);
          out[(size_t)row * 256 + col] = v;
        }
      }
    }
  }
}

// ------- final: fused gather2 + dual GEMM (512 -> 47) + log_softmax, 4 rows/block -------
__global__ __launch_bounds__(64) void final_fused_k(
    const float* __restrict__ h1, const int* __restrict__ ss,
    const int* __restrict__ rs, const float* __restrict__ Wl,
    const float* __restrict__ Wr, const float* __restrict__ bb,
    float* __restrict__ out) {
  __shared__ float sm[4][256];
  __shared__ float sx[4][256];
  const int i0 = blockIdx.x * 4;
  const int f = threadIdx.x;
#pragma unroll
  for (int r = 0; r < 4; ++r) {
    const int i = i0 + r;
    const int lo = rs[i];
    const int hi = rs[i + 1];
    float a0 = 0.f, a1 = 0.f, a2 = 0.f, a3 = 0.f;
    for (int e = lo; e < hi; ++e) {
      const float* p = h1 + (size_t)ss[e] * 256;
      a0 += p[f]; a1 += p[f + 64]; a2 += p[f + 128]; a3 += p[f + 192];
    }
    const float inv = 1.f / (float)max(hi - lo, 1);
    sm[r][f] = a0 * inv; sm[r][f + 64] = a1 * inv;
    sm[r][f + 128] = a2 * inv; sm[r][f + 192] = a3 * inv;
    const float* q = h1 + (size_t)i * 256;
    sx[r][f] = q[f]; sx[r][f + 64] = q[f + 64];
    sx[r][f + 128] = q[f + 128]; sx[r][f + 192] = q[f + 192];
  }
  __syncthreads();

  const int j = f;
  float acc[4] = {-1e30f, -1e30f, -1e30f, -1e30f};
  if (j < 47) {
    float b = bb[j];
    acc[0] = b; acc[1] = b; acc[2] = b; acc[3] = b;
    for (int k = 0; k < 256; ++k) {
      float wl = Wl[k * 47 + j];
      float wr = Wr[k * 47 + j];
#pragma unroll
      for (int r = 0; r < 4; ++r) acc[r] += sm[r][k] * wl + sx[r][k] * wr;
    }
  }
#pragma unroll
  for (int r = 0; r < 4; ++r) {
    float m = acc[r];
#pragma unroll
    for (int off = 32; off; off >>= 1) m = fmaxf(m, __shfl_xor(m, off));
    float e = (j < 47) ? expf(acc[r] - m) : 0.f;
    float s = e;
#pragma unroll
    for (int off = 32; off; off >>= 1) s += __shfl_xor(s, off);
    if (j < 47) out[(size_t)(i0 + r) * 47 + j] = acc[r] - m - logf(s);
  }
}

extern "C" void kernel_launch(void* const* d_in, const int* in_sizes, int n_in,
                              void* d_out, int out_size, void* d_ws, size_t ws_size,
                              hipStream_t stream) {
  const float* x    = (const float*)d_in[0];
  const int*   src0 = (const int*)d_in[1];
  const int*   dst0 = (const int*)d_in[2];
  const int*   src1 = (const int*)d_in[3];
  const int*   dst1 = (const int*)d_in[4];
  const int*   src2 = (const int*)d_in[5];
  const int*   dst2 = (const int*)d_in[6];
  const float* Wl0  = (const float*)d_in[7];
  const float* Wr0  = (const float*)d_in[8];
  const float* b0   = (const float*)d_in[9];
  const float* Wl1  = (const float*)d_in[10];
  const float* Wr1  = (const float*)d_in[11];
  const float* b1   = (const float*)d_in[12];
  const float* Wl2  = (const float*)d_in[13];
  const float* Wr2  = (const float*)d_in[14];
  const float* b2   = (const float*)d_in[15];
  float* out = (float*)d_out;

  const int E0 = in_sizes[1];  // 900000
  const int E1 = in_sizes[3];  // 60000
  const int E2 = in_sizes[5];  // 5120
  const int N0 = 60000, N1 = 6000, N2 = 1024;

  // ---- workspace carve-up ----
  char* base = (char*)d_ws;
  unsigned short* am0 = (unsigned short*)(base);            // 60032 x 224 bf16
  unsigned short* bm0 = (unsigned short*)(base + 26894336); // 28x256x8 bf16
  float* h0           = (float*)(base + 27009024);          // 60032 x 256 f32
  unsigned short* am1 = (unsigned short*)(base + 88481792); // 6016 x 512 bf16
  unsigned short* bm1 = (unsigned short*)(base + 94642176); // 64x256x8 bf16
  float* h1           = (float*)(base + 94904320);          // 6016 x 256 f32
  int* iw   = (int*)(base + 102113280);
  int* row0 = iw;                       // 60001
  int* row1 = row0 + 60001;             // 6001
  int* row2 = row1 + 6001;              // 1025
  int* cnt0 = row2 + 1025;              // 60000 } contiguous: one memset
  int* cnt1 = cnt0 + 60000;             // 6000  }
  int* cnt2 = cnt1 + 6000;              // 1024  }
  int* cur0 = cnt2 + 1024;              // 60000
  int* cur1 = cur0 + 60000;             // 6000
  int* cur2 = cur1 + 6000;              // 1024
  int* ss0  = cur2 + 1024;              // 900000
  int* ss1  = ss0 + 900000;             // 60000
  int* ss2  = ss1 + 60000;              // 5120

  hipMemsetAsync(cnt0, 0, (size_t)67024 * sizeof(int), stream);

  const int ET = E0 + E1 + E2;
  hist3_k<<<(ET + 255) / 256, 256, 0, stream>>>(dst0, dst1, dst2, cnt0, cnt1, cnt2,
                                                E0, E1, E2);
  scan3_k<<<3, 1024, 0, stream>>>(cnt0, row0, cur0, cnt1, row1, cur1,
                                  cnt2, row2, cur2, N0, N1, N2);
  fill3_k<<<(ET + 255) / 256, 256, 0, stream>>>(src0, dst0, src1, dst1, src2, dst2,
                                                cur0, cur1, cur2, ss0, ss1, ss2,
                                                E0, E1, E2);
  pack2_k<<<224 + 512, 256, 0, stream>>>(Wl0, Wr0, bm0, Wl1, Wr1, bm1);

  // ---- Layer 0 ----
  gather_fused_k<100, 224, 112><<<(N0 * 64 + 255) / 256, 256, 0, stream>>>(
      x, x, ss0, row0, am0, N0);
  gemm_mfma_k<224, 64, true><<<(N0 + 63) / 64, 256, 0, stream>>>(
      am0, bm0, b0, h0, N0);

  // ---- Layer 1 ----
  gather_fused_k<256, 512, 256><<<(N1 * 64 + 255) / 256, 256, 0, stream>>>(
      h0, h0, ss1, row1, am1, N1);
  gemm_mfma_k<512, 32, true><<<(N1 + 31) / 32, 256, 0, stream>>>(
      am1, bm1, b1, h1, N1);

  // ---- Layer 2 (fused final) ----
  final_fused_k<<<N2 / 4, 64, 0, stream>>>(h1, ss2, row2, Wl2, Wr2, b2, out);
}